// Round 1
// 671.458 us; speedup vs baseline: 1.0623x; 1.0623x over previous
//
#include <hip/hip_runtime.h>

#define NBATCH 16
#define CH 512
#define HID 32
#define KTOP 153
#define SP 4096
#define NELEM (NBATCH*CH*SP)   // 33554432

typedef __bf16 bf16x8 __attribute__((ext_vector_type(8)));
typedef float f32x16 __attribute__((ext_vector_type(16)));

__device__ __forceinline__ unsigned short f2bf(float f) {
    union { float f; unsigned u; } v; v.f = f;
    unsigned r = v.u + 0x7FFFu + ((v.u >> 16) & 1u);   // RNE
    return (unsigned short)(r >> 16);
}

// ---------------------------------------------------------------------------
// K1: pure spatial reduce. One wave per (b, branch, ch): 4096 floats summed
// via float4 + butterfly shuffle. No LDS, no barriers, no transpose output.
// grid (128 ch-quads, 32 = b*2+branch), block 256 (4 waves = 4 channels).
// ---------------------------------------------------------------------------
__global__ __launch_bounds__(256) void k1_reduce(
    const float* __restrict__ xt, const float* __restrict__ xc,
    float* __restrict__ psum)
{
    int c4 = blockIdx.x, bz = blockIdx.y;
    int b = bz >> 1, br = bz & 1;
    const float* x = br ? xc : xt;
    int t = threadIdx.x, lane = t & 63, w = t >> 6;
    int ch = c4 * 4 + w;
    const float4* p = (const float4*)(x + ((size_t)b * CH + ch) * SP);
    float s = 0.f;
    #pragma unroll
    for (int k = 0; k < 16; ++k) {
        float4 v = p[lane + k * 64];
        s += ((v.x + v.y) + (v.z + v.w));
    }
    #pragma unroll
    for (int off = 32; off; off >>= 1) s += __shfl_xor(s, off, 64);
    if (lane == 0) psum[(size_t)(br * 16 + b) * CH + ch] = s;
}

// ---------------------------------------------------------------------------
// K2a: SE MLP (fp32), sigmoid, exact top-153 mask. psum is now fully reduced.
// grid (16 b, 2 branch), block 512.
// ---------------------------------------------------------------------------
__global__ __launch_bounds__(512) void k2_se(
    const float* __restrict__ psum,
    const float* __restrict__ w1t, const float* __restrict__ b1t,
    const float* __restrict__ w2t, const float* __restrict__ b2t,
    const float* __restrict__ w1c, const float* __restrict__ b1c,
    const float* __restrict__ w2c, const float* __restrict__ b2c,
    float* __restrict__ sAt, float* __restrict__ sBt, float* __restrict__ attc)
{
    int b = blockIdx.x, br = blockIdx.y;
    int bb = br * 16 + b;
    int t = threadIdx.x;
    __shared__ float satt[512];
    __shared__ float ph[16][33];
    __shared__ float sh[32];
    __shared__ float sval[512];

    satt[t] = psum[(size_t)bb * CH + t] * (1.0f / 4096.0f);
    __syncthreads();

    const float* w1 = br ? w1c : w1t; const float* b1 = br ? b1c : b1t;
    const float* w2 = br ? w2c : w2t; const float* b2 = br ? b2c : b2t;

    {
        int j = t & 31, seg = t >> 5;
        float hp = 0.f;
        #pragma unroll
        for (int i = 0; i < 32; ++i)
            hp += satt[seg * 32 + i] * w1[(seg * 32 + i) * HID + j];
        ph[seg][j] = hp;
    }
    __syncthreads();
    if (t < HID) {
        float h = b1[t];
        #pragma unroll
        for (int sgi = 0; sgi < 16; ++sgi) h += ph[sgi][t];
        sh[t] = fmaxf(h, 0.0f);
    }
    __syncthreads();

    float z = b2[t];
    #pragma unroll
    for (int j = 0; j < HID; ++j) z += sh[j] * w2[j * CH + t];
    float a = 1.0f / (1.0f + expf(-z));

    if (br == 0) {
        sval[t] = a;
        __syncthreads();
        int cnt = 0;
        for (int j = 0; j < CH; ++j) {
            float o = sval[j];
            cnt += (o > a) || (o == a && j < t);   // matches top_k tie order
        }
        sAt[b * CH + t] = a;
        sBt[b * CH + t] = (cnt < KTOP) ? 1.0f : 0.0f;
    } else {
        attc[b * CH + t] = a;
    }
}

// ---------------------------------------------------------------------------
// K2b: softmax rows of cross_att -> bf16 W, PRE-SWIZZLED to MFMA A-fragment
// granule order: granule(m,k8): pos = ((kb*16 + (m>>5))*2 + ks)*64 + hi*32 + (m&31)
// grid 512 rows, block 64. (unchanged)
// ---------------------------------------------------------------------------
__global__ __launch_bounds__(64) void k2_softmax(
    const float* __restrict__ ca, unsigned short* __restrict__ wswz)
{
    int trow = blockIdx.x;
    int lane = threadIdx.x;
    const float* row = ca + (size_t)trow * CH;
    float v[8];
    #pragma unroll
    for (int i = 0; i < 8; ++i) v[i] = row[lane * 8 + i];
    float m = v[0];
    #pragma unroll
    for (int i = 1; i < 8; ++i) m = fmaxf(m, v[i]);
    #pragma unroll
    for (int off = 32; off; off >>= 1) m = fmaxf(m, __shfl_xor(m, off, 64));
    float s = 0.f;
    #pragma unroll
    for (int i = 0; i < 8; ++i) { v[i] = expf(v[i] - m); s += v[i]; }
    #pragma unroll
    for (int off = 32; off; off >>= 1) s += __shfl_xor(s, off, 64);
    float inv = 1.0f / s;

    int k = lane * 8;
    int kb = k >> 5, ks = (k >> 4) & 1, hi = (k >> 3) & 1;
    int p = ((kb * 16 + (trow >> 5)) * 2 + ks) * 64 + hi * 32 + (trow & 31);
    unsigned short* dst = wswz + (size_t)p * 8;
    ushort4 lo, hm;
    lo.x = f2bf(v[0] * inv); lo.y = f2bf(v[1] * inv);
    lo.z = f2bf(v[2] * inv); lo.w = f2bf(v[3] * inv);
    hm.x = f2bf(v[4] * inv); hm.y = f2bf(v[5] * inv);
    hm.z = f2bf(v[6] * inv); hm.w = f2bf(v[7] * inv);
    *(ushort4*)dst = lo;
    *(ushort4*)(dst + 4) = hm;
}

// ---------------------------------------------------------------------------
// K3: FUSED dual-branch GEMM + epilogue.
// One block = one (b, 32-wide spatial tile), BOTH branches.
//  - stage x_t and x_c tiles fp32->bf16 into LDS as [n=32][k=512],
//    XOR-swizzled (byte ^= (n&7)<<4) so ds_read_b128 fragments hit the
//    4-cycle LDS floor instead of a 32-way bank conflict (row stride 1024 B)
//  - single barrier; K-loop: A fragments from pre-swizzled wswz (L2-hot,
//    512 KiB, shared by BOTH accumulators), B fragments from LDS
//  - epilogue re-reads fp32 x from global (cache-warm: this block just
//    fetched those lines) and streams out_t/out_c with nontemporal stores.
// grid (128 n-tiles, 16 b), block 256 (4 waves, M-split 4x128).
// LDS 64 KiB -> 2 blocks/CU.
// ---------------------------------------------------------------------------
__global__ __launch_bounds__(256, 2) void k3_fused(
    const float* __restrict__ xt, const float* __restrict__ xc,
    const unsigned short* __restrict__ wswz,
    const float* __restrict__ sAt, const float* __restrict__ sBt,
    const float* __restrict__ attc,
    float* __restrict__ out)
{
    int nt = blockIdx.x, b = blockIdx.y;
    int t = threadIdx.x, lane = t & 63, w = t >> 6;
    int n0 = nt * 32;

    __shared__ unsigned short B2[2][32 * 512];   // [src][n][k] bf16, swizzled

    // ---- staging: thread owns (s-quad a, ch-quad cq) per 128-ch block ----
    {
        int a  = t & 7;          // spatial quad: n = a*4 + j
        int cq = t >> 3;         // channel quad within 128-ch block
        #pragma unroll
        for (int src = 0; src < 2; ++src) {
            const float* x = src ? xc : xt;
            char* bl = (char*)B2[src];
            const float* gbase = x + (size_t)b * CH * SP + n0 + a * 4;
            #pragma unroll
            for (int chb = 0; chb < 4; ++chb) {
                int q = chb * 32 + cq;                 // k-quad 0..127
                float4 v0 = *(const float4*)(gbase + (size_t)(q * 4 + 0) * SP);
                float4 v1 = *(const float4*)(gbase + (size_t)(q * 4 + 1) * SP);
                float4 v2 = *(const float4*)(gbase + (size_t)(q * 4 + 2) * SP);
                float4 v3 = *(const float4*)(gbase + (size_t)(q * 4 + 3) * SP);
                #pragma unroll
                for (int j = 0; j < 4; ++j) {
                    int n = a * 4 + j;
                    ushort4 d;
                    d.x = f2bf(((const float*)&v0)[j]);
                    d.y = f2bf(((const float*)&v1)[j]);
                    d.z = f2bf(((const float*)&v2)[j]);
                    d.w = f2bf(((const float*)&v3)[j]);
                    int bo = n * 1024 + ((q * 8) ^ ((n & 7) << 4));
                    *(ushort4*)(bl + bo) = d;
                }
            }
        }
    }
    __syncthreads();

    // ---- GEMM: D_t = W @ Bc, D_c = W @ Bt ; A fragments shared ----
    f32x16 acct[4], accc[4];
    #pragma unroll
    for (int r = 0; r < 4; ++r)
        #pragma unroll
        for (int e = 0; e < 16; ++e) { acct[r][e] = 0.0f; accc[r][e] = 0.0f; }

    // A granule (kb,r,ks): wswz + (((kb*16 + (w*4+r))*2 + ks)*64 + lane)*8
    const unsigned short* abase = wswz + ((size_t)(w * 4 * 2 * 64 + lane)) * 8;
    const char* btl = (const char*)B2[0];
    const char* bcl = (const char*)B2[1];
    int nb = (lane & 31) * 1024;
    int xr = (lane & 7) << 4;          // (n&7)<<4, n = lane&31
    int kf = (lane >> 5) * 16;         // byte offset of this half-wave's k8

    bf16x8 afr[2][8], bft[2][2], bfc[2][2];

    #pragma unroll
    for (int r = 0; r < 4; ++r)
        #pragma unroll
        for (int ks = 0; ks < 2; ++ks)
            afr[0][r * 2 + ks] = *(const bf16x8*)(abase + r * 1024 + ks * 512);
    #pragma unroll
    for (int ks = 0; ks < 2; ++ks) {
        int off = nb + ((ks * 32 + kf) ^ xr);
        bft[0][ks] = *(const bf16x8*)(btl + off);
        bfc[0][ks] = *(const bf16x8*)(bcl + off);
    }

    #pragma unroll
    for (int kb = 0; kb < 16; ++kb) {
        int cur = kb & 1, nxt = cur ^ 1;
        if (kb < 15) {
            #pragma unroll
            for (int r = 0; r < 4; ++r)
                #pragma unroll
                for (int ks = 0; ks < 2; ++ks)
                    afr[nxt][r * 2 + ks] =
                        *(const bf16x8*)(abase + (kb + 1) * 16384 + r * 1024 + ks * 512);
            #pragma unroll
            for (int ks = 0; ks < 2; ++ks) {
                int off = nb + ((((kb + 1) * 64) + ks * 32 + kf) ^ xr);
                bft[nxt][ks] = *(const bf16x8*)(btl + off);
                bfc[nxt][ks] = *(const bf16x8*)(bcl + off);
            }
        }
        #pragma unroll
        for (int ks = 0; ks < 2; ++ks)
            #pragma unroll
            for (int r = 0; r < 4; ++r) {
                acct[r] = __builtin_amdgcn_mfma_f32_32x32x16_bf16(
                    afr[cur][r * 2 + ks], bfc[cur][ks], acct[r], 0, 0, 0);
                accc[r] = __builtin_amdgcn_mfma_f32_32x32x16_bf16(
                    afr[cur][r * 2 + ks], bft[cur][ks], accc[r], 0, 0, 0);
            }
    }

    // ---- epilogue: C/D row=(reg&3)+8*(reg>>2)+4*(lane>>5), col=lane&31 ----
    int colb = n0 + (lane & 31);
    int rowq = 4 * (lane >> 5);
    #pragma unroll
    for (int r = 0; r < 4; ++r) {
        #pragma unroll
        for (int reg = 0; reg < 16; ++reg) {
            int m = w * 128 + r * 32 + (reg & 3) + 8 * (reg >> 2) + rowq;
            size_t idx = ((size_t)b * CH + m) * SP + colb;
            float at = sAt[b * CH + m];
            float bt = sBt[b * CH + m];
            float ac = attc[b * CH + m];
            float ot = at * xt[idx] + bt * acct[r][reg];
            float oc = ac * xc[idx] + ac * accc[r][reg];
            __builtin_nontemporal_store(ot, &out[idx]);
            __builtin_nontemporal_store(oc, &out[NELEM + idx]);
        }
    }
}

// ---------------------------------------------------------------------------
extern "C" void kernel_launch(void* const* d_in, const int* in_sizes, int n_in,
                              void* d_out, int out_size, void* d_ws, size_t ws_size,
                              hipStream_t stream)
{
    const float* xt  = (const float*)d_in[0];
    const float* xc  = (const float*)d_in[1];
    const float* w1t = (const float*)d_in[2];
    const float* b1t = (const float*)d_in[3];
    const float* w2t = (const float*)d_in[4];
    const float* b2t = (const float*)d_in[5];
    const float* w1c = (const float*)d_in[6];
    const float* b1c = (const float*)d_in[7];
    const float* w2c = (const float*)d_in[8];
    const float* b2c = (const float*)d_in[9];
    const float* ca  = (const float*)d_in[10];
    float* out = (float*)d_out;
    char* ws = (char*)d_ws;

    unsigned short* wswz = (unsigned short*)(ws);              // 512 KiB
    float* psum = (float*)(ws + 524288ull);                    // 64 KiB
    float* sAt  = (float*)(ws + 589824ull);                    // 32 KiB
    float* sBt  = (float*)(ws + 622592ull);                    // 32 KiB
    float* attc = (float*)(ws + 655360ull);                    // 32 KiB

    hipLaunchKernelGGL(k1_reduce, dim3(128, 32), dim3(256), 0, stream,
                       xt, xc, psum);
    hipLaunchKernelGGL(k2_se, dim3(16, 2), dim3(512), 0, stream,
                       psum, w1t, b1t, w2t, b2t, w1c, b1c, w2c, b2c, sAt, sBt, attc);
    hipLaunchKernelGGL(k2_softmax, dim3(512), dim3(64), 0, stream, ca, wswz);
    hipLaunchKernelGGL(k3_fused, dim3(128, 16), dim3(256), 0, stream,
                       xt, xc, wswz, sAt, sBt, attc, out);
}